// Round 20
// baseline (165.948 us; speedup 1.0000x reference)
//
#include <hip/hip_runtime.h>
#include <math.h>

#define EPSF 1e-12f
// N=32, HW=1024, D=512, K=64, OUT=4096, KD=32768

typedef __attribute__((ext_vector_type(8))) short short8v;  // 8 bf16
typedef __attribute__((ext_vector_type(4))) float f32x4;

__device__ __forceinline__ unsigned short f2bf(float f) {   // RNE
    unsigned int u = __float_as_uint(f);
    return (unsigned short)((u + 0x7FFF + ((u >> 16) & 1)) >> 16);
}
__device__ __forceinline__ float bf2f(unsigned short h) {
    return __uint_as_float(((unsigned int)h) << 16);
}

// ---- kernel 0: w1 -> w1t hi/lo bf16 [64 k][512 d]; C -> Ct [64 k][512 d] --
__global__ __launch_bounds__(256) void k_prep(
    const float* __restrict__ w1, const float* __restrict__ C,
    unsigned short* __restrict__ w1t_h, unsigned short* __restrict__ w1t_l,
    float* __restrict__ Ct)
{
    const int i  = blockIdx.x * 256 + threadIdx.x;   // 0..8191
    const int k  = i >> 7;
    const int d0 = (i & 127) << 2;
    float vv[4], cc[4];
#pragma unroll
    for (int j = 0; j < 4; ++j) {
        vv[j] = w1[(size_t)(d0 + j) * 64 + k];
        cc[j] = C [(size_t)(d0 + j) * 64 + k];
    }
    ushort4 h, l;
    h.x = f2bf(vv[0]); l.x = f2bf(vv[0] - bf2f(h.x));
    h.y = f2bf(vv[1]); l.y = f2bf(vv[1] - bf2f(h.y));
    h.z = f2bf(vv[2]); l.z = f2bf(vv[2] - bf2f(h.z));
    h.w = f2bf(vv[3]); l.w = f2bf(vv[3] - bf2f(h.w));
    *(ushort4*)(w1t_h + (size_t)k * 512 + d0) = h;
    *(ushort4*)(w1t_l + (size_t)k * 512 + d0) = l;
    *(float4*)(Ct + (size_t)k * 512 + d0) = make_float4(cc[0], cc[1], cc[2], cc[3]);
}

// ---- kernel 1: logits = x @ W1 (split-bf16 MFMA) + in-register softmax ----
// (r19-proven: w1t staged through LDS, MFMA section LDS-only)
__global__ __launch_bounds__(256) void k_assign(
    const float* __restrict__ x,
    const unsigned short* __restrict__ w1t_h,
    const unsigned short* __restrict__ w1t_l,
    const float* __restrict__ b1,
    unsigned short* __restrict__ st_h, unsigned short* __restrict__ st_l,
    float* __restrict__ ap)
{
    const int tid  = threadIdx.x;
    const int lane = tid & 63;
    const int wv   = __builtin_amdgcn_readfirstlane(tid >> 6);  // 0..3
    const int l4   = lane >> 4;
    const int l16  = lane & 15;
    const int pix0 = blockIdx.x * 64;
    const int n_img  = blockIdx.x >> 4;
    const int p_base = (blockIdx.x & 15) * 64;

    __shared__ unsigned short Xh[64][72];   // +8 pad: conflict-free b128
    __shared__ unsigned short Xl[64][72];
    __shared__ unsigned short Wh[64][72];   // w1t chunk [k][64 dd], padded
    __shared__ unsigned short Wl[64][72];
    __shared__ float apred[4][64];

    f32x4 acc[4];
#pragma unroll
    for (int nf = 0; nf < 4; ++nf) acc[nf] = (f32x4){0.f, 0.f, 0.f, 0.f};

    float4  xr[4];
    short8v wrh[2], wrl[2];
#pragma unroll
    for (int t = 0; t < 4; ++t) {            // prologue: x chunk 0 -> regs
        int idx = tid + t * 256, p = idx >> 4, d4 = (idx & 15) << 2;
        xr[t] = *(const float4*)&x[(size_t)(pix0 + p) * 512 + d4];
    }
#pragma unroll
    for (int q = 0; q < 2; ++q) {            // prologue: w1t chunk 0 -> regs
        int i = (q * 256 + tid) * 8, k = i >> 6, dd = i & 63;
        wrh[q] = *(const short8v*)(w1t_h + (size_t)k * 512 + dd);
        wrl[q] = *(const short8v*)(w1t_l + (size_t)k * 512 + dd);
    }

    for (int c = 0; c < 8; ++c) {
#pragma unroll
        for (int t = 0; t < 4; ++t) {        // x cvt + write LDS
            int idx = tid + t * 256, p = idx >> 4, d4 = (idx & 15) << 2;
            float4 v = xr[t];
            ushort4 h4, l4v;
            h4.x = f2bf(v.x); l4v.x = f2bf(v.x - bf2f(h4.x));
            h4.y = f2bf(v.y); l4v.y = f2bf(v.y - bf2f(h4.y));
            h4.z = f2bf(v.z); l4v.z = f2bf(v.z - bf2f(h4.z));
            h4.w = f2bf(v.w); l4v.w = f2bf(v.w - bf2f(h4.w));
            *(ushort4*)&Xh[p][d4] = h4;
            *(ushort4*)&Xl[p][d4] = l4v;
        }
#pragma unroll
        for (int q = 0; q < 2; ++q) {        // w1t chunk -> LDS
            int i = (q * 256 + tid) * 8, k = i >> 6, dd = i & 63;
            *(short8v*)&Wh[k][dd] = wrh[q];
            *(short8v*)&Wl[k][dd] = wrl[q];
        }
        if (c + 1 < 8) {                     // prefetch chunk c+1 (x + w1t)
#pragma unroll
            for (int t = 0; t < 4; ++t) {
                int idx = tid + t * 256, p = idx >> 4, d4 = (idx & 15) << 2;
                xr[t] = *(const float4*)&x[(size_t)(pix0 + p) * 512 +
                                           (c + 1) * 64 + d4];
            }
#pragma unroll
            for (int q = 0; q < 2; ++q) {
                int i = (q * 256 + tid) * 8, k = i >> 6, dd = i & 63;
                wrh[q] = *(const short8v*)(w1t_h + (size_t)k * 512 +
                                           (c + 1) * 64 + dd);
                wrl[q] = *(const short8v*)(w1t_l + (size_t)k * 512 +
                                           (c + 1) * 64 + dd);
            }
        }
        __syncthreads();                     // LDS writes visible
#pragma unroll
        for (int ks = 0; ks < 2; ++ks) {     // 2 k-steps of 32 d, LDS-only
            short8v ah = *(const short8v*)&Xh[wv * 16 + l16][ks * 32 + l4 * 8];
            short8v al = *(const short8v*)&Xl[wv * 16 + l16][ks * 32 + l4 * 8];
#pragma unroll
            for (int nf = 0; nf < 4; ++nf) {
                short8v bh = *(const short8v*)&Wh[nf * 16 + l16][ks * 32 + l4 * 8];
                short8v bl = *(const short8v*)&Wl[nf * 16 + l16][ks * 32 + l4 * 8];
                acc[nf] = __builtin_amdgcn_mfma_f32_16x16x32_bf16(ah, bh, acc[nf], 0, 0, 0);
                acc[nf] = __builtin_amdgcn_mfma_f32_16x16x32_bf16(ah, bl, acc[nf], 0, 0, 0);
                acc[nf] = __builtin_amdgcn_mfma_f32_16x16x32_bf16(al, bh, acc[nf], 0, 0, 0);
            }
        }
        __syncthreads();                     // reads done before next writes
    }

    // epilogue: +b1, softmax over k (px = wv*16 + 4*l4 + r, k = nf*16 + l16)
    float lg[4][4];                          // [nf][r]
#pragma unroll
    for (int nf = 0; nf < 4; ++nf) {
        const float bb = b1[nf * 16 + l16];
#pragma unroll
        for (int r = 0; r < 4; ++r) lg[nf][r] = acc[nf][r] + bb;
    }
    float mx[4], sm[4];
#pragma unroll
    for (int r = 0; r < 4; ++r)
        mx[r] = fmaxf(fmaxf(lg[0][r], lg[1][r]), fmaxf(lg[2][r], lg[3][r]));
#pragma unroll
    for (int m = 1; m <= 8; m <<= 1)
#pragma unroll
        for (int r = 0; r < 4; ++r) mx[r] = fmaxf(mx[r], __shfl_xor(mx[r], m, 64));
#pragma unroll
    for (int r = 0; r < 4; ++r) sm[r] = 0.f;
#pragma unroll
    for (int nf = 0; nf < 4; ++nf)
#pragma unroll
        for (int r = 0; r < 4; ++r) { lg[nf][r] = __expf(lg[nf][r] - mx[r]); sm[r] += lg[nf][r]; }
#pragma unroll
    for (int m = 1; m <= 8; m <<= 1)
#pragma unroll
        for (int r = 0; r < 4; ++r) sm[r] += __shfl_xor(sm[r], m, 64);

    // s values -> st (transposed, split) + ap partials
#pragma unroll
    for (int nf = 0; nf < 4; ++nf) {
        float sv[4];
        ushort4 hh, ll;
#pragma unroll
        for (int r = 0; r < 4; ++r) sv[r] = lg[nf][r] * (1.0f / sm[r]);
        hh.x = f2bf(sv[0]); ll.x = f2bf(sv[0] - bf2f(hh.x));
        hh.y = f2bf(sv[1]); ll.y = f2bf(sv[1] - bf2f(hh.y));
        hh.z = f2bf(sv[2]); ll.z = f2bf(sv[2] - bf2f(hh.z));
        hh.w = f2bf(sv[3]); ll.w = f2bf(sv[3] - bf2f(hh.w));
        const size_t so = (size_t)(n_img * 64 + nf * 16 + l16) * 1024 +
                          p_base + wv * 16 + l4 * 4;
        *(ushort4*)(st_h + so) = hh;
        *(ushort4*)(st_l + so) = ll;
        float tsum = sv[0] + sv[1] + sv[2] + sv[3];
        tsum += __shfl_xor(tsum, 16, 64);
        tsum += __shfl_xor(tsum, 32, 64);
        if (l4 == 0) apred[wv][nf * 16 + l16] = tsum;
    }
    __syncthreads();
    if (tid < 64)
        ap[(size_t)blockIdx.x * 64 + tid] =
            (apred[0][tid] + apred[1][tid]) + (apred[2][tid] + apred[3][tid]);
}

// ---- kernel 2: vpart[pq][k][d] = sum_{p in quarter pq} st[k][p]*x[p][d] ---
// r20: QUARTER split (grid 2048 = n x pq(4) x dc(16) -> 4 waves/SIMD, was
// 2) + counted-vmcnt 3-buffer (r14 gemm2 template: A-loads first,
// STAGE(t+2), vmcnt(2) keeps t+2's loads in flight across the barrier).
// r19's vmcnt(0)-drain exposed ~200cy+ per iter (compute ~700cy < 900cy
// RTT). k_norm sums 4 quarters.
__global__ __launch_bounds__(128) void k_vlad(
    const unsigned short* __restrict__ st_h,
    const unsigned short* __restrict__ st_l,
    const float* __restrict__ x, float* __restrict__ vpart)
{
    __shared__ float X2[3][32][32];          // 12 KB triple-buffered

    const int tid  = threadIdx.x;
    const int lane = tid & 63;
    const int w    = __builtin_amdgcn_readfirstlane(tid >> 6);  // 0/1
    const int l4   = lane >> 4;
    const int l16  = lane & 15;
    const int b    = blockIdx.x;
    const int n    = b >> 6;
    const int pq   = (b >> 4) & 3;
    const int dc   = b & 15;
    const int dbase = dc * 32;
    const int pbase = n * 1024 + pq * 256;

    f32x4 acc[4];                            // [mf]
#pragma unroll
    for (int mf = 0; mf < 4; ++mf) acc[mf] = (f32x4){0.f, 0.f, 0.f, 0.f};

#define VSTAGE(T_, B_)                                                        \
    do {                                                                      \
        _Pragma("unroll")                                                     \
        for (int i_ = 0; i_ < 2; ++i_) {                                      \
            const int jj_ = w * 2 + i_;                                       \
            __builtin_amdgcn_global_load_lds(                                 \
                (const __attribute__((address_space(1))) void*)               \
                    (x + (size_t)(pbase + (T_) * 32 + jj_ * 8 +               \
                                  (lane >> 3)) * 512 + dbase + (lane & 7) * 4), \
                (__attribute__((address_space(3))) void*)&X2[B_][jj_ * 8][0], \
                16, 0, 0);                                                    \
        }                                                                     \
    } while (0)

    VSTAGE(0, 0);
    VSTAGE(1, 1);
    asm volatile("s_waitcnt vmcnt(2)" ::: "memory");   // tile 0 resident
    __builtin_amdgcn_sched_barrier(0);
    __builtin_amdgcn_s_barrier();

    for (int t = 0; t < 8; ++t) {
        const int cur = t % 3;

        // A-fragments FIRST (in-order vmcnt: waits here retire tile t+1's
        // stages too, but NOT t+2's, issued below)
        const size_t sbase = (size_t)(n * 64) * 1024 + pq * 256 + t * 32 + l4 * 8;
        short8v ah[4], al[4];
#pragma unroll
        for (int mf = 0; mf < 4; ++mf) {
            ah[mf] = *(const short8v*)(st_h + sbase + (size_t)(mf * 16 + l16) * 1024);
            al[mf] = *(const short8v*)(st_l + sbase + (size_t)(mf * 16 + l16) * 1024);
        }

        if (t + 2 < 8) VSTAGE(t + 2, (t + 2) % 3);

        short8v bh, bl;
#pragma unroll
        for (int j = 0; j < 8; ++j) {
            float bx = X2[cur][l4 * 8 + j][w * 16 + l16];
            unsigned short hb = f2bf(bx);
            bh[j] = (short)hb;
            bl[j] = (short)f2bf(bx - bf2f(hb));
        }
#pragma unroll
        for (int mf = 0; mf < 4; ++mf) {
            acc[mf] = __builtin_amdgcn_mfma_f32_16x16x32_bf16(ah[mf], bh, acc[mf], 0, 0, 0);
            acc[mf] = __builtin_amdgcn_mfma_f32_16x16x32_bf16(ah[mf], bl, acc[mf], 0, 0, 0);
            acc[mf] = __builtin_amdgcn_mfma_f32_16x16x32_bf16(al[mf], bh, acc[mf], 0, 0, 0);
        }

        if (t + 2 < 8) {
            asm volatile("s_waitcnt vmcnt(2)" ::: "memory");  // t+1 resident
        } else {
            asm volatile("s_waitcnt vmcnt(0)" ::: "memory");  // tail drain
        }
        __builtin_amdgcn_sched_barrier(0);
        __builtin_amdgcn_s_barrier();
    }
#undef VSTAGE

#pragma unroll
    for (int mf = 0; mf < 4; ++mf)
#pragma unroll
        for (int r = 0; r < 4; ++r)
            vpart[(size_t)pq * 1048576 +
                  (size_t)(n * 64 + mf * 16 + 4 * l4 + r) * 512 +
                  dbase + w * 16 + l16] = acc[mf][r];
}

// ---- kernel 3: vn16 = bf16( intra-L2-norm(sum vpart[0..3] + a*Ct) /8 ) ----
__global__ __launch_bounds__(256) void k_norm(
    const float* __restrict__ vpart, const float* __restrict__ ap,
    const float* __restrict__ Ct, unsigned short* __restrict__ vn16)
{
    const int lane = threadIdx.x & 63;
    const int w    = threadIdx.x >> 6;
    const int row  = blockIdx.x * 4 + w;   // n*64 + k
    const int n    = row >> 6;
    const int k    = row & 63;

    float a_nk = 0.f;
#pragma unroll
    for (int t = 0; t < 16; ++t)
        a_nk += ap[((size_t)(n * 16 + t)) * 64 + k];

    const float* vr0 = vpart + (size_t)row * 512;
    const float* vr1 = vr0 + 1048576;
    const float* vr2 = vr0 + 2097152;
    const float* vr3 = vr0 + 3145728;
    const float* cr  = Ct + (size_t)k * 512;
    float vv[8];
    float ss = 0.f;
#pragma unroll
    for (int j = 0; j < 8; ++j) {
        int d = j * 64 + lane;
        float t = ((vr0[d] + vr1[d]) + (vr2[d] + vr3[d])) + a_nk * cr[d];
        vv[j] = t;
        ss = fmaf(t, t, ss);
    }
#pragma unroll
    for (int off = 32; off > 0; off >>= 1) ss += __shfl_xor(ss, off, 64);
    const float scale = rsqrtf(fmaxf(ss, EPSF)) * 0.125f;
    unsigned short* vo = vn16 + (size_t)row * 512;
#pragma unroll
    for (int j = 0; j < 8; ++j) vo[j * 64 + lane] = f2bf(vv[j] * scale);
}

// ---- kernel 4: outpart[kc] = vn @ W2 slice (bf16 MFMA, r14 schedule) ------
// MEASURED (r15, 5x-launch): 83.6 µs ~= the 81 µs HBM floor — at roofline.
__global__ __launch_bounds__(256, 2) void k_gemm2(
    const unsigned short* __restrict__ vn16, const float* __restrict__ w2,
    float* __restrict__ outpart)
{
    __shared__ float Bs[3][32][128];   // 48 KB triple-buffered w2 tile

    const int tid  = threadIdx.x;
    const int lane = tid & 63;
    const int wv   = __builtin_amdgcn_readfirstlane(tid >> 6);  // 0..3
    const int kc   = blockIdx.x >> 5;
    const int cb   = blockIdx.x & 31;
    const int rowbase = kc * 2048;
    const int colbase = cb * 128;
    const int l4   = lane >> 4;
    const int l16  = lane & 15;

    f32x4 acc[2][2];
#pragma unroll
    for (int i = 0; i < 2; ++i)
#pragma unroll
        for (int j = 0; j < 2; ++j)
            acc[i][j] = (f32x4){0.f, 0.f, 0.f, 0.f};

#define STAGE(T_, B_)                                                         \
    do {                                                                      \
        _Pragma("unroll")                                                     \
        for (int i_ = 0; i_ < 4; ++i_) {                                      \
            const int r_ = (wv * 4 + i_) * 2 + (lane >> 5);                   \
            __builtin_amdgcn_global_load_lds(                                 \
                (const __attribute__((address_space(1))) void*)               \
                    (w2 + (size_t)(rowbase + (T_) * 32 + r_) * 4096 +         \
                     colbase + (lane & 31) * 4),                              \
                (__attribute__((address_space(3))) void*)                     \
                    &Bs[B_][(wv * 4 + i_) * 2][0],                            \
                16, 0, 0);                                                    \
        }                                                                     \
    } while (0)

    STAGE(0, 0);
    STAGE(1, 1);
    asm volatile("s_waitcnt vmcnt(4)" ::: "memory");   // tile 0 resident
    __builtin_amdgcn_sched_barrier(0);
    __builtin_amdgcn_s_barrier();

    for (int t = 0; t < 64; ++t) {
        const int cur = t % 3;

        const unsigned short* va = vn16 + (size_t)(rowbase + t * 32 + l4 * 8);
        short8v a0 = *(const short8v*)(va + (size_t)l16 * 32768);
        short8v a1 = *(const short8v*)(va + (size_t)(16 + l16) * 32768);

        if (t + 2 < 64) STAGE(t + 2, (t + 2) % 3);

#pragma unroll
        for (int nf = 0; nf < 2; ++nf) {
            const int cl = wv * 32 + nf * 16 + l16;
            short8v bfr;
#pragma unroll
            for (int j = 0; j < 8; ++j)
                bfr[j] = (short)f2bf(Bs[cur][l4 * 8 + j][cl]);
            acc[0][nf] = __builtin_amdgcn_mfma_f32_16x16x32_bf16(
                a0, bfr, acc[0][nf], 0, 0, 0);
            acc[1][nf] = __builtin_amdgcn_mfma_f32_16x16x32_bf16(
                a1, bfr, acc[1][nf], 0, 0, 0);
        }

        if (t + 2 < 64) {
            asm volatile("s_waitcnt vmcnt(4)" ::: "memory");
        } else {
            asm volatile("s_waitcnt vmcnt(0)" ::: "memory");
        }
        __builtin_amdgcn_sched_barrier(0);
        __builtin_amdgcn_s_barrier();
    }
#undef STAGE

#pragma unroll
    for (int mf = 0; mf < 2; ++mf)
#pragma unroll
        for (int nf = 0; nf < 2; ++nf)
#pragma unroll
            for (int r = 0; r < 4; ++r) {
                const int m  = mf * 16 + l4 * 4 + r;
                const int cl = colbase + wv * 32 + nf * 16 + l16;
                outpart[(size_t)kc * 131072 + (size_t)m * 4096 + cl] =
                    acc[mf][nf][r];
            }
}

// ---- kernel 5: reduce 16 partials + bias, per-block sumsq -----------------
__global__ __launch_bounds__(256) void k_reduce(
    const float* __restrict__ outpart, const float* __restrict__ b2,
    float* __restrict__ out, float* __restrict__ ssp)
{
    const int i = (blockIdx.x * 256 + threadIdx.x) * 4;
    float4 o = make_float4(0.f, 0.f, 0.f, 0.f);
#pragma unroll
    for (int kc = 0; kc < 16; ++kc) {
        float4 t = *(const float4*)&outpart[(size_t)kc * 131072 + i];
        o.x += t.x; o.y += t.y; o.z += t.z; o.w += t.w;
    }
    float4 bb = *(const float4*)&b2[i & 4095];
    o.x += bb.x; o.y += bb.y; o.z += bb.z; o.w += bb.w;
    *(float4*)&out[i] = o;

    float ss = o.x * o.x + o.y * o.y + o.z * o.z + o.w * o.w;
#pragma unroll
    for (int off = 32; off > 0; off >>= 1) ss += __shfl_xor(ss, off, 64);
    __shared__ float lred[4];
    if ((threadIdx.x & 63) == 0) lred[threadIdx.x >> 6] = ss;
    __syncthreads();
    if (threadIdx.x == 0)
        ssp[blockIdx.x] = lred[0] + lred[1] + lred[2] + lred[3];
}

// ---- kernel 6: global L2 scale --------------------------------------------
__global__ __launch_bounds__(256) void k_scale(
    const float* __restrict__ ssp, float* __restrict__ out)
{
    float ss = 0.f;
#pragma unroll
    for (int t = 0; t < 128; ++t) ss += ssp[t];
    const float sc = rsqrtf(fmaxf(ss, EPSF));
    const int i = (blockIdx.x * 256 + threadIdx.x) * 4;
    float4 o = *(float4*)&out[i];
    o.x *= sc; o.y *= sc; o.z *= sc; o.w *= sc;
    *(float4*)&out[i] = o;
}

extern "C" void kernel_launch(void* const* d_in, const int* in_sizes, int n_in,
                              void* d_out, int out_size, void* d_ws, size_t ws_size,
                              hipStream_t stream)
{
    const float* x  = (const float*)d_in[0];
    const float* w1 = (const float*)d_in[1];
    const float* b1 = (const float*)d_in[2];
    const float* C  = (const float*)d_in[3];
    const float* w2 = (const float*)d_in[4];
    const float* b2 = (const float*)d_in[5];
    float* out = (float*)d_out;
    float* ws  = (float*)d_ws;

    // ws layout (floats) — FLAT, no overlays (ws_size ~2 GiB). Total 36 MB.
    unsigned short* st_h  = (unsigned short*)ws;                 // [0, 1M)
    unsigned short* st_l  = (unsigned short*)(ws + 1048576);     // [1M, 2M)
    float*          vpart = ws + 2097152;                        // [2M, 6M)
    unsigned short* w1t_h = (unsigned short*)(ws + 6291456);     // 16384 f
    unsigned short* w1t_l = (unsigned short*)(ws + 6307840);     // 16384 f
    float*          Ct    = ws + 6324224;                        // 32768 f
    float*          ap    = ws + 6356992;                        // 32768 f
    float*          ssp   = ws + 6389760;                        // 128 f
    unsigned short* vn16  = (unsigned short*)(ws + 6389888);     // 524288 f
    float*          outpart = ws + 6914176;                      // 2M f

    k_prep  <<<32,   256, 0, stream>>>(w1, C, w1t_h, w1t_l, Ct);
    k_assign<<<512,  256, 0, stream>>>(x, w1t_h, w1t_l, b1, st_h, st_l, ap);
    k_vlad  <<<2048, 128, 0, stream>>>(st_h, st_l, x, vpart);
    k_norm  <<<512,  256, 0, stream>>>(vpart, ap, Ct, vn16);
    k_gemm2 <<<512,  256, 0, stream>>>(vn16, w2, outpart);
    k_reduce<<<128,  256, 0, stream>>>(outpart, b2, out, ssp);
    k_scale <<<128,  256, 0, stream>>>(ssp, out);
}

// Round 21
// 160.068 us; speedup vs baseline: 1.0367x; 1.0367x over previous
//
#include <hip/hip_runtime.h>
#include <math.h>

#define EPSF 1e-12f
// N=32, HW=1024, D=512, K=64, OUT=4096, KD=32768

typedef __attribute__((ext_vector_type(8))) short short8v;  // 8 bf16
typedef __attribute__((ext_vector_type(4))) float f32x4;

__device__ __forceinline__ unsigned short f2bf(float f) {   // RNE
    unsigned int u = __float_as_uint(f);
    return (unsigned short)((u + 0x7FFF + ((u >> 16) & 1)) >> 16);
}
__device__ __forceinline__ float bf2f(unsigned short h) {
    return __uint_as_float(((unsigned int)h) << 16);
}

// ---- kernel 0: w1 -> w1t hi/lo bf16 [64 k][512 d]; C -> Ct [64 k][512 d] --
__global__ __launch_bounds__(256) void k_prep(
    const float* __restrict__ w1, const float* __restrict__ C,
    unsigned short* __restrict__ w1t_h, unsigned short* __restrict__ w1t_l,
    float* __restrict__ Ct)
{
    const int i  = blockIdx.x * 256 + threadIdx.x;   // 0..8191
    const int k  = i >> 7;
    const int d0 = (i & 127) << 2;
    float vv[4], cc[4];
#pragma unroll
    for (int j = 0; j < 4; ++j) {
        vv[j] = w1[(size_t)(d0 + j) * 64 + k];
        cc[j] = C [(size_t)(d0 + j) * 64 + k];
    }
    ushort4 h, l;
    h.x = f2bf(vv[0]); l.x = f2bf(vv[0] - bf2f(h.x));
    h.y = f2bf(vv[1]); l.y = f2bf(vv[1] - bf2f(h.y));
    h.z = f2bf(vv[2]); l.z = f2bf(vv[2] - bf2f(h.z));
    h.w = f2bf(vv[3]); l.w = f2bf(vv[3] - bf2f(h.w));
    *(ushort4*)(w1t_h + (size_t)k * 512 + d0) = h;
    *(ushort4*)(w1t_l + (size_t)k * 512 + d0) = l;
    *(float4*)(Ct + (size_t)k * 512 + d0) = make_float4(cc[0], cc[1], cc[2], cc[3]);
}

// ---- kernel 1: logits = x @ W1 (split-bf16 MFMA) + in-register softmax ----
// (r19-proven: w1t staged through LDS, MFMA section LDS-only)
__global__ __launch_bounds__(256) void k_assign(
    const float* __restrict__ x,
    const unsigned short* __restrict__ w1t_h,
    const unsigned short* __restrict__ w1t_l,
    const float* __restrict__ b1,
    unsigned short* __restrict__ st_h, unsigned short* __restrict__ st_l,
    float* __restrict__ ap)
{
    const int tid  = threadIdx.x;
    const int lane = tid & 63;
    const int wv   = __builtin_amdgcn_readfirstlane(tid >> 6);  // 0..3
    const int l4   = lane >> 4;
    const int l16  = lane & 15;
    const int pix0 = blockIdx.x * 64;
    const int n_img  = blockIdx.x >> 4;
    const int p_base = (blockIdx.x & 15) * 64;

    __shared__ unsigned short Xh[64][72];   // +8 pad: conflict-free b128
    __shared__ unsigned short Xl[64][72];
    __shared__ unsigned short Wh[64][72];   // w1t chunk [k][64 dd], padded
    __shared__ unsigned short Wl[64][72];
    __shared__ float apred[4][64];

    f32x4 acc[4];
#pragma unroll
    for (int nf = 0; nf < 4; ++nf) acc[nf] = (f32x4){0.f, 0.f, 0.f, 0.f};

    float4  xr[4];
    short8v wrh[2], wrl[2];
#pragma unroll
    for (int t = 0; t < 4; ++t) {            // prologue: x chunk 0 -> regs
        int idx = tid + t * 256, p = idx >> 4, d4 = (idx & 15) << 2;
        xr[t] = *(const float4*)&x[(size_t)(pix0 + p) * 512 + d4];
    }
#pragma unroll
    for (int q = 0; q < 2; ++q) {            // prologue: w1t chunk 0 -> regs
        int i = (q * 256 + tid) * 8, k = i >> 6, dd = i & 63;
        wrh[q] = *(const short8v*)(w1t_h + (size_t)k * 512 + dd);
        wrl[q] = *(const short8v*)(w1t_l + (size_t)k * 512 + dd);
    }

    for (int c = 0; c < 8; ++c) {
#pragma unroll
        for (int t = 0; t < 4; ++t) {        // x cvt + write LDS
            int idx = tid + t * 256, p = idx >> 4, d4 = (idx & 15) << 2;
            float4 v = xr[t];
            ushort4 h4, l4v;
            h4.x = f2bf(v.x); l4v.x = f2bf(v.x - bf2f(h4.x));
            h4.y = f2bf(v.y); l4v.y = f2bf(v.y - bf2f(h4.y));
            h4.z = f2bf(v.z); l4v.z = f2bf(v.z - bf2f(h4.z));
            h4.w = f2bf(v.w); l4v.w = f2bf(v.w - bf2f(h4.w));
            *(ushort4*)&Xh[p][d4] = h4;
            *(ushort4*)&Xl[p][d4] = l4v;
        }
#pragma unroll
        for (int q = 0; q < 2; ++q) {        // w1t chunk -> LDS
            int i = (q * 256 + tid) * 8, k = i >> 6, dd = i & 63;
            *(short8v*)&Wh[k][dd] = wrh[q];
            *(short8v*)&Wl[k][dd] = wrl[q];
        }
        if (c + 1 < 8) {                     // prefetch chunk c+1 (x + w1t)
#pragma unroll
            for (int t = 0; t < 4; ++t) {
                int idx = tid + t * 256, p = idx >> 4, d4 = (idx & 15) << 2;
                xr[t] = *(const float4*)&x[(size_t)(pix0 + p) * 512 +
                                           (c + 1) * 64 + d4];
            }
#pragma unroll
            for (int q = 0; q < 2; ++q) {
                int i = (q * 256 + tid) * 8, k = i >> 6, dd = i & 63;
                wrh[q] = *(const short8v*)(w1t_h + (size_t)k * 512 +
                                           (c + 1) * 64 + dd);
                wrl[q] = *(const short8v*)(w1t_l + (size_t)k * 512 +
                                           (c + 1) * 64 + dd);
            }
        }
        __syncthreads();                     // LDS writes visible
#pragma unroll
        for (int ks = 0; ks < 2; ++ks) {     // 2 k-steps of 32 d, LDS-only
            short8v ah = *(const short8v*)&Xh[wv * 16 + l16][ks * 32 + l4 * 8];
            short8v al = *(const short8v*)&Xl[wv * 16 + l16][ks * 32 + l4 * 8];
#pragma unroll
            for (int nf = 0; nf < 4; ++nf) {
                short8v bh = *(const short8v*)&Wh[nf * 16 + l16][ks * 32 + l4 * 8];
                short8v bl = *(const short8v*)&Wl[nf * 16 + l16][ks * 32 + l4 * 8];
                acc[nf] = __builtin_amdgcn_mfma_f32_16x16x32_bf16(ah, bh, acc[nf], 0, 0, 0);
                acc[nf] = __builtin_amdgcn_mfma_f32_16x16x32_bf16(ah, bl, acc[nf], 0, 0, 0);
                acc[nf] = __builtin_amdgcn_mfma_f32_16x16x32_bf16(al, bh, acc[nf], 0, 0, 0);
            }
        }
        __syncthreads();                     // reads done before next writes
    }

    // epilogue: +b1, softmax over k (px = wv*16 + 4*l4 + r, k = nf*16 + l16)
    float lg[4][4];                          // [nf][r]
#pragma unroll
    for (int nf = 0; nf < 4; ++nf) {
        const float bb = b1[nf * 16 + l16];
#pragma unroll
        for (int r = 0; r < 4; ++r) lg[nf][r] = acc[nf][r] + bb;
    }
    float mx[4], sm[4];
#pragma unroll
    for (int r = 0; r < 4; ++r)
        mx[r] = fmaxf(fmaxf(lg[0][r], lg[1][r]), fmaxf(lg[2][r], lg[3][r]));
#pragma unroll
    for (int m = 1; m <= 8; m <<= 1)
#pragma unroll
        for (int r = 0; r < 4; ++r) mx[r] = fmaxf(mx[r], __shfl_xor(mx[r], m, 64));
#pragma unroll
    for (int r = 0; r < 4; ++r) sm[r] = 0.f;
#pragma unroll
    for (int nf = 0; nf < 4; ++nf)
#pragma unroll
        for (int r = 0; r < 4; ++r) { lg[nf][r] = __expf(lg[nf][r] - mx[r]); sm[r] += lg[nf][r]; }
#pragma unroll
    for (int m = 1; m <= 8; m <<= 1)
#pragma unroll
        for (int r = 0; r < 4; ++r) sm[r] += __shfl_xor(sm[r], m, 64);

    // s values -> st (transposed, split) + ap partials
#pragma unroll
    for (int nf = 0; nf < 4; ++nf) {
        float sv[4];
        ushort4 hh, ll;
#pragma unroll
        for (int r = 0; r < 4; ++r) sv[r] = lg[nf][r] * (1.0f / sm[r]);
        hh.x = f2bf(sv[0]); ll.x = f2bf(sv[0] - bf2f(hh.x));
        hh.y = f2bf(sv[1]); ll.y = f2bf(sv[1] - bf2f(hh.y));
        hh.z = f2bf(sv[2]); ll.z = f2bf(sv[2] - bf2f(hh.z));
        hh.w = f2bf(sv[3]); ll.w = f2bf(sv[3] - bf2f(hh.w));
        const size_t so = (size_t)(n_img * 64 + nf * 16 + l16) * 1024 +
                          p_base + wv * 16 + l4 * 4;
        *(ushort4*)(st_h + so) = hh;
        *(ushort4*)(st_l + so) = ll;
        float tsum = sv[0] + sv[1] + sv[2] + sv[3];
        tsum += __shfl_xor(tsum, 16, 64);
        tsum += __shfl_xor(tsum, 32, 64);
        if (l4 == 0) apred[wv][nf * 16 + l16] = tsum;
    }
    __syncthreads();
    if (tid < 64)
        ap[(size_t)blockIdx.x * 64 + tid] =
            (apred[0][tid] + apred[1][tid]) + (apred[2][tid] + apred[3][tid]);
}

// ---- kernel 2: vpart[ph][k][d] = sum_{p in half ph} st[k][p]*x[p][d] ------
// (r19-proven: pixel-half split, 2 waves/SIMD; r20's quarter-split + counted
// vmcnt regressed +5.4µs — per-block overhead and vpart traffic scaled
// faster than the occupancy gain)
__global__ __launch_bounds__(128) void k_vlad(
    const unsigned short* __restrict__ st_h,
    const unsigned short* __restrict__ st_l,
    const float* __restrict__ x, float* __restrict__ vpart)
{
    __shared__ float X2[2][32][32];          // 8 KB double-buffered

    const int tid  = threadIdx.x;
    const int lane = tid & 63;
    const int w    = __builtin_amdgcn_readfirstlane(tid >> 6);  // 0/1
    const int l4   = lane >> 4;
    const int l16  = lane & 15;
    const int b    = blockIdx.x;
    const int n    = b >> 5;
    const int ph   = (b >> 4) & 1;
    const int dc   = b & 15;
    const int dbase = dc * 32;
    const int pbase = n * 1024 + ph * 512;

    f32x4 acc[4];                            // [mf]
#pragma unroll
    for (int mf = 0; mf < 4; ++mf) acc[mf] = (f32x4){0.f, 0.f, 0.f, 0.f};

#define VSTAGE(T_, B_)                                                        \
    do {                                                                      \
        _Pragma("unroll")                                                     \
        for (int i_ = 0; i_ < 2; ++i_) {                                      \
            const int jj_ = w * 2 + i_;                                       \
            __builtin_amdgcn_global_load_lds(                                 \
                (const __attribute__((address_space(1))) void*)               \
                    (x + (size_t)(pbase + (T_) * 32 + jj_ * 8 +               \
                                  (lane >> 3)) * 512 + dbase + (lane & 7) * 4), \
                (__attribute__((address_space(3))) void*)&X2[B_][jj_ * 8][0], \
                16, 0, 0);                                                    \
        }                                                                     \
    } while (0)

    VSTAGE(0, 0);
    __syncthreads();

    int buf = 0;
    for (int t = 0; t < 16; ++t) {
        if (t + 1 < 16) VSTAGE(t + 1, buf ^ 1);

        const size_t sbase = (size_t)(n * 64) * 1024 + ph * 512 + t * 32 + l4 * 8;
        short8v ah[4], al[4];
#pragma unroll
        for (int mf = 0; mf < 4; ++mf) {
            ah[mf] = *(const short8v*)(st_h + sbase + (size_t)(mf * 16 + l16) * 1024);
            al[mf] = *(const short8v*)(st_l + sbase + (size_t)(mf * 16 + l16) * 1024);
        }
        short8v bh, bl;
#pragma unroll
        for (int j = 0; j < 8; ++j) {
            float bx = X2[buf][l4 * 8 + j][w * 16 + l16];
            unsigned short hb = f2bf(bx);
            bh[j] = (short)hb;
            bl[j] = (short)f2bf(bx - bf2f(hb));
        }
#pragma unroll
        for (int mf = 0; mf < 4; ++mf) {
            acc[mf] = __builtin_amdgcn_mfma_f32_16x16x32_bf16(ah[mf], bh, acc[mf], 0, 0, 0);
            acc[mf] = __builtin_amdgcn_mfma_f32_16x16x32_bf16(ah[mf], bl, acc[mf], 0, 0, 0);
            acc[mf] = __builtin_amdgcn_mfma_f32_16x16x32_bf16(al[mf], bh, acc[mf], 0, 0, 0);
        }
        __syncthreads();
        buf ^= 1;
    }
#undef VSTAGE

#pragma unroll
    for (int mf = 0; mf < 4; ++mf)
#pragma unroll
        for (int r = 0; r < 4; ++r)
            vpart[(size_t)ph * 1048576 +
                  (size_t)(n * 64 + mf * 16 + 4 * l4 + r) * 512 +
                  dbase + w * 16 + l16] = acc[mf][r];
}

// ---- kernel 3: vn16 = bf16( intra-L2-norm(vp0 + vp1 + a*Ct) * 1/8 ) -------
__global__ __launch_bounds__(256) void k_norm(
    const float* __restrict__ vpart, const float* __restrict__ ap,
    const float* __restrict__ Ct, unsigned short* __restrict__ vn16)
{
    const int lane = threadIdx.x & 63;
    const int w    = threadIdx.x >> 6;
    const int row  = blockIdx.x * 4 + w;   // n*64 + k
    const int n    = row >> 6;
    const int k    = row & 63;

    float a_nk = 0.f;
#pragma unroll
    for (int t = 0; t < 16; ++t)
        a_nk += ap[((size_t)(n * 16 + t)) * 64 + k];

    const float* vr0 = vpart + (size_t)row * 512;
    const float* vr1 = vr0 + 1048576;
    const float* cr  = Ct + (size_t)k * 512;
    float vv[8];
    float ss = 0.f;
#pragma unroll
    for (int j = 0; j < 8; ++j) {
        int d = j * 64 + lane;
        float t = (vr0[d] + vr1[d]) + a_nk * cr[d];
        vv[j] = t;
        ss = fmaf(t, t, ss);
    }
#pragma unroll
    for (int off = 32; off > 0; off >>= 1) ss += __shfl_xor(ss, off, 64);
    const float scale = rsqrtf(fmaxf(ss, EPSF)) * 0.125f;
    unsigned short* vo = vn16 + (size_t)row * 512;
#pragma unroll
    for (int j = 0; j < 8; ++j) vo[j * 64 + lane] = f2bf(vv[j] * scale);
}

// ---- kernel 4: outpart[kc] = vn @ W2 slice (bf16 MFMA, r14 schedule) ------
// MEASURED (r15, 5x-launch): 83.6 µs ~= the 81 µs HBM floor — at roofline.
__global__ __launch_bounds__(256, 2) void k_gemm2(
    const unsigned short* __restrict__ vn16, const float* __restrict__ w2,
    float* __restrict__ outpart)
{
    __shared__ float Bs[3][32][128];   // 48 KB triple-buffered w2 tile

    const int tid  = threadIdx.x;
    const int lane = tid & 63;
    const int wv   = __builtin_amdgcn_readfirstlane(tid >> 6);  // 0..3
    const int kc   = blockIdx.x >> 5;
    const int cb   = blockIdx.x & 31;
    const int rowbase = kc * 2048;
    const int colbase = cb * 128;
    const int l4   = lane >> 4;
    const int l16  = lane & 15;

    f32x4 acc[2][2];
#pragma unroll
    for (int i = 0; i < 2; ++i)
#pragma unroll
        for (int j = 0; j < 2; ++j)
            acc[i][j] = (f32x4){0.f, 0.f, 0.f, 0.f};

#define STAGE(T_, B_)                                                         \
    do {                                                                      \
        _Pragma("unroll")                                                     \
        for (int i_ = 0; i_ < 4; ++i_) {                                      \
            const int r_ = (wv * 4 + i_) * 2 + (lane >> 5);                   \
            __builtin_amdgcn_global_load_lds(                                 \
                (const __attribute__((address_space(1))) void*)               \
                    (w2 + (size_t)(rowbase + (T_) * 32 + r_) * 4096 +         \
                     colbase + (lane & 31) * 4),                              \
                (__attribute__((address_space(3))) void*)                     \
                    &Bs[B_][(wv * 4 + i_) * 2][0],                            \
                16, 0, 0);                                                    \
        }                                                                     \
    } while (0)

    STAGE(0, 0);
    STAGE(1, 1);
    asm volatile("s_waitcnt vmcnt(4)" ::: "memory");   // tile 0 resident
    __builtin_amdgcn_sched_barrier(0);
    __builtin_amdgcn_s_barrier();

    for (int t = 0; t < 64; ++t) {
        const int cur = t % 3;

        const unsigned short* va = vn16 + (size_t)(rowbase + t * 32 + l4 * 8);
        short8v a0 = *(const short8v*)(va + (size_t)l16 * 32768);
        short8v a1 = *(const short8v*)(va + (size_t)(16 + l16) * 32768);

        if (t + 2 < 64) STAGE(t + 2, (t + 2) % 3);

#pragma unroll
        for (int nf = 0; nf < 2; ++nf) {
            const int cl = wv * 32 + nf * 16 + l16;
            short8v bfr;
#pragma unroll
            for (int j = 0; j < 8; ++j)
                bfr[j] = (short)f2bf(Bs[cur][l4 * 8 + j][cl]);
            acc[0][nf] = __builtin_amdgcn_mfma_f32_16x16x32_bf16(
                a0, bfr, acc[0][nf], 0, 0, 0);
            acc[1][nf] = __builtin_amdgcn_mfma_f32_16x16x32_bf16(
                a1, bfr, acc[1][nf], 0, 0, 0);
        }

        if (t + 2 < 64) {
            asm volatile("s_waitcnt vmcnt(4)" ::: "memory");
        } else {
            asm volatile("s_waitcnt vmcnt(0)" ::: "memory");
        }
        __builtin_amdgcn_sched_barrier(0);
        __builtin_amdgcn_s_barrier();
    }
#undef STAGE

#pragma unroll
    for (int mf = 0; mf < 2; ++mf)
#pragma unroll
        for (int nf = 0; nf < 2; ++nf)
#pragma unroll
            for (int r = 0; r < 4; ++r) {
                const int m  = mf * 16 + l4 * 4 + r;
                const int cl = colbase + wv * 32 + nf * 16 + l16;
                outpart[(size_t)kc * 131072 + (size_t)m * 4096 + cl] =
                    acc[mf][nf][r];
            }
}

// ---- kernel 5: reduce 16 partials + bias, per-block sumsq -----------------
__global__ __launch_bounds__(256) void k_reduce(
    const float* __restrict__ outpart, const float* __restrict__ b2,
    float* __restrict__ out, float* __restrict__ ssp)
{
    const int i = (blockIdx.x * 256 + threadIdx.x) * 4;
    float4 o = make_float4(0.f, 0.f, 0.f, 0.f);
#pragma unroll
    for (int kc = 0; kc < 16; ++kc) {
        float4 t = *(const float4*)&outpart[(size_t)kc * 131072 + i];
        o.x += t.x; o.y += t.y; o.z += t.z; o.w += t.w;
    }
    float4 bb = *(const float4*)&b2[i & 4095];
    o.x += bb.x; o.y += bb.y; o.z += bb.z; o.w += bb.w;
    *(float4*)&out[i] = o;

    float ss = o.x * o.x + o.y * o.y + o.z * o.z + o.w * o.w;
#pragma unroll
    for (int off = 32; off > 0; off >>= 1) ss += __shfl_xor(ss, off, 64);
    __shared__ float lred[4];
    if ((threadIdx.x & 63) == 0) lred[threadIdx.x >> 6] = ss;
    __syncthreads();
    if (threadIdx.x == 0)
        ssp[blockIdx.x] = lred[0] + lred[1] + lred[2] + lred[3];
}

// ---- kernel 6: global L2 scale --------------------------------------------
__global__ __launch_bounds__(256) void k_scale(
    const float* __restrict__ ssp, float* __restrict__ out)
{
    float ss = 0.f;
#pragma unroll
    for (int t = 0; t < 128; ++t) ss += ssp[t];
    const float sc = rsqrtf(fmaxf(ss, EPSF));
    const int i = (blockIdx.x * 256 + threadIdx.x) * 4;
    float4 o = *(float4*)&out[i];
    o.x *= sc; o.y *= sc; o.z *= sc; o.w *= sc;
    *(float4*)&out[i] = o;
}

extern "C" void kernel_launch(void* const* d_in, const int* in_sizes, int n_in,
                              void* d_out, int out_size, void* d_ws, size_t ws_size,
                              hipStream_t stream)
{
    const float* x  = (const float*)d_in[0];
    const float* w1 = (const float*)d_in[1];
    const float* b1 = (const float*)d_in[2];
    const float* C  = (const float*)d_in[3];
    const float* w2 = (const float*)d_in[4];
    const float* b2 = (const float*)d_in[5];
    float* out = (float*)d_out;
    float* ws  = (float*)d_ws;

    // ws layout (floats) — FLAT, no overlays (ws_size ~2 GiB). Total 27.7 MB.
    unsigned short* st_h  = (unsigned short*)ws;                 // [0, 1M)
    unsigned short* st_l  = (unsigned short*)(ws + 1048576);     // [1M, 2M)
    float*          vpart = ws + 2097152;                        // [2M, 4M)
    unsigned short* w1t_h = (unsigned short*)(ws + 4194304);     // 16384 f
    unsigned short* w1t_l = (unsigned short*)(ws + 4210688);     // 16384 f
    float*          Ct    = ws + 4227072;                        // 32768 f
    float*          ap    = ws + 4259840;                        // 32768 f
    float*          ssp   = ws + 4292608;                        // 128 f
    unsigned short* vn16  = (unsigned short*)(ws + 4292736);     // 524288 f
    float*          outpart = ws + 4817024;                      // 2M f

    k_prep  <<<32,   256, 0, stream>>>(w1, C, w1t_h, w1t_l, Ct);
    k_assign<<<512,  256, 0, stream>>>(x, w1t_h, w1t_l, b1, st_h, st_l, ap);
    k_vlad  <<<1024, 128, 0, stream>>>(st_h, st_l, x, vpart);
    k_norm  <<<512,  256, 0, stream>>>(vpart, ap, Ct, vn16);
    k_gemm2 <<<512,  256, 0, stream>>>(vn16, w2, outpart);
    k_reduce<<<128,  256, 0, stream>>>(outpart, b2, out, ssp);
    k_scale <<<128,  256, 0, stream>>>(ssp, out);
}